// Round 5
// baseline (201.227 us; speedup 1.0000x reference)
//
#include <hip/hip_runtime.h>
#include <hip/hip_bf16.h>
#include <stdint.h>

// out = x @ W^T + bias; W[f,n] = sum_k scale[k,f]*(bit(7-n%8) of binary[k,f,n/8] ? +1 : -1)
// Round 5: kill the LDS<->MFMA convoy by removing A from LDS entirely.
// A-fragments load global->VGPR (same addrs for all 4 waves -> L1 reuse);
// B double-buffered in LDS (2x32KB) with T2 swizzle. Per-CU LDS reads drop
// ~3x below the MFMA floor, so even a serialized schedule sits near 16.6us.
// 128x256 tile, 4 waves (wave-tile 128x64), grid 512 = 2 blocks/CU.

#define BITS 8
#define NF   4096
#define NXX  1024
#define GRP  (NXX / 8)

#define BM 128
#define BN 256
#define BK 64

typedef __attribute__((ext_vector_type(4))) float f32x4;
typedef __attribute__((ext_vector_type(8))) short bf16x8;

// ---------------- prep: cast x (blocks 0..2047) + decode W (blocks 2048..4095) ----
__global__ __launch_bounds__(256) void k_prep(const float* __restrict__ x,
                                              const int* __restrict__ binary,
                                              const float* __restrict__ scale,
                                              __hip_bfloat16* __restrict__ xb,
                                              __hip_bfloat16* __restrict__ Wb) {
    const int b = blockIdx.x;
    const int tid = threadIdx.x;
    if (b < 2048) {
        int i = b * 256 + tid;
        const float4* xp = (const float4*)x;
        float4 a = xp[2 * i], c = xp[2 * i + 1];
        union { __hip_bfloat16 h[8]; int4 v; } u;
        u.h[0] = __float2bfloat16(a.x);
        u.h[1] = __float2bfloat16(a.y);
        u.h[2] = __float2bfloat16(a.z);
        u.h[3] = __float2bfloat16(a.w);
        u.h[4] = __float2bfloat16(c.x);
        u.h[5] = __float2bfloat16(c.y);
        u.h[6] = __float2bfloat16(c.z);
        u.h[7] = __float2bfloat16(c.w);
        ((int4*)xb)[i] = u.v;
    } else {
        int idx = (b - 2048) * 256 + tid;       // 0 .. NF*GRP-1
        int f = idx >> 7;                       // GRP = 128
        int g = idx & (GRP - 1);
        float sc[BITS];
        int   bv[BITS];
#pragma unroll
        for (int k = 0; k < BITS; ++k) {
            sc[k] = scale[k * NF + f];
            bv[k] = binary[(size_t)(k * NF + f) * GRP + g];
        }
        union { __hip_bfloat16 h[8]; int4 v; } u;
#pragma unroll
        for (int j = 0; j < 8; ++j) {           // element j uses bit (7-j)
            float s = 0.f;
#pragma unroll
            for (int k = 0; k < BITS; ++k)
                s += ((bv[k] >> (7 - j)) & 1) ? sc[k] : -sc[k];
            u.h[j] = __float2bfloat16(s);
        }
        ((int4*)Wb)[idx] = u.v;
    }
}

// ---------------- GEMM: C[M,N] = A[M,K] * B[N,K]^T + bias ----------------
// 256 thr = 4 waves; wave w owns N-cols [w*64, w*64+64), all 128 M-rows.
// A-frags: global->VGPR, aFa (m 0..63) + aFb (m 64..127), each 8 x b128,
// reloaded for tile t+1 right after their last use in tile t.
// B: LDS double-buffer 2x32KB, T2 swizzle, gload_lds staging, raw s_barrier
// + manual vmcnt(16) (stage(t) = oldest 8 of 24 outstanding VMEM ops).
__global__ __launch_bounds__(256, 2) void k_gemm(const __hip_bfloat16* __restrict__ A,
                                                 const __hip_bfloat16* __restrict__ B,
                                                 const float* __restrict__ bias,
                                                 float* __restrict__ C,
                                                 int M, int N, int K) {
    __shared__ __align__(16) char lds[65536];   // 2 x 32KB B buffers

    const int tid  = threadIdx.x;
    const int lane = tid & 63;
    const int wv   = tid >> 6;      // 0..3
    const int lr = lane & 15;       // fragment row/col
    const int lk = lane >> 4;       // K-octet 0..3

    // T1: XCD swizzle. grid=512, 64 blocks/XCD: m fast-varying within XCD.
    const int bid = blockIdx.x;
    const int swz = (bid & 7) * 64 + (bid >> 3);
    const int m0 = (swz & 31) * BM;
    const int n0 = (swz >> 5) * BN;

    const int NT = K / BK;          // 16

    // B staging constants (T2: source chunk pre-swizzled, LDS dest linear)
    int offB[8], dstB[8];
#pragma unroll
    for (int j = 0; j < 8; ++j) {
        int c = j * 256 + tid, r = c >> 3, q = c & 7;
        offB[j] = r * K + (q ^ (r & 7)) * 8;
        dstB[j] = c * 16;
    }
    const __hip_bfloat16* Bbase = B + (size_t)n0 * K;
    // per-lane A base: row m0+lr, K-offset lk*8
    const __hip_bfloat16* Aptr = A + (size_t)(m0 + lr) * K + lk * 8;

    auto stageB = [&](int buf, int kt) {
#pragma unroll
        for (int j = 0; j < 8; ++j)
            __builtin_amdgcn_global_load_lds(
                (const __attribute__((address_space(1))) void*)(Bbase + offB[j] + kt),
                (__attribute__((address_space(3))) void*)(lds + buf * 32768 + dstB[j]), 16, 0, 0);
    };
    // swizzled LDS read: logical (row R, col-byte CB) -> CB ^ ((R&7)<<4)
    auto ldB = [&](int buf, int j, int kk) -> bf16x8 {
        int R = wv * 64 + j * 16 + lr;
        int CB = (kk * 64 + lk * 16) ^ ((R & 7) << 4);
        return *(const bf16x8*)(lds + buf * 32768 + R * 128 + CB);
    };

    f32x4 acc[8][4] = {};
    bf16x8 aFa[4][2], aFb[4][2], bF[4][2];

    auto loadAa = [&](int kt) {
#pragma unroll
        for (int i = 0; i < 4; ++i)
#pragma unroll
            for (int kk = 0; kk < 2; ++kk)
                aFa[i][kk] = *(const bf16x8*)(Aptr + (size_t)(i * 16) * K + kt + kk * 32);
    };
    auto loadAb = [&](int kt) {
#pragma unroll
        for (int i = 0; i < 4; ++i)
#pragma unroll
            for (int kk = 0; kk < 2; ++kk)
                aFb[i][kk] = *(const bf16x8*)(Aptr + (size_t)((i + 4) * 16) * K + kt + kk * 32);
    };

    // prologue: stage B(0), then A(0) halves (stages must be OLDEST VMEM ops)
    stageB(0, 0);
    __builtin_amdgcn_sched_barrier(0);
    loadAa(0);
    __builtin_amdgcn_sched_barrier(0);
    loadAb(0);
    __builtin_amdgcn_sched_barrier(0);

    for (int t = 0; t < NT; ++t) {
        const int cb = t & 1;
        const bool st = (t + 1 < NT);
        // retire stage(t): outstanding = stage(t)8 + aFa(t)8 + aFb(t)8 = 24
        asm volatile("s_waitcnt vmcnt(16)" ::: "memory");
        __builtin_amdgcn_s_barrier();
        __builtin_amdgcn_sched_barrier(0);      // no read hoisting above barrier

        // B fragments for this tile (compiler emits counted lgkm before MFMA use)
#pragma unroll
        for (int j = 0; j < 4; ++j) { bF[j][0] = ldB(cb, j, 0); bF[j][1] = ldB(cb, j, 1); }
        // stage next B tile into other buffer (readers of it passed barrier above)
        if (st) stageB(cb ^ 1, (t + 1) * BK);
        __builtin_amdgcn_sched_barrier(0);

        // MFMA half A (m 0..63) — consumes aFa(t)
        __builtin_amdgcn_s_setprio(1);
#pragma unroll
        for (int i = 0; i < 4; ++i)
#pragma unroll
            for (int j = 0; j < 4; ++j)
#pragma unroll
                for (int kk = 0; kk < 2; ++kk)
                    acc[i][j] = __builtin_amdgcn_mfma_f32_16x16x32_bf16(
                        aFa[i][kk], bF[j][kk], acc[i][j], 0, 0, 0);
        __builtin_amdgcn_s_setprio(0);
        __builtin_amdgcn_sched_barrier(0);
        // reload aFa for t+1 (last use was above; 32 MFMA ≈1242cyc covers latency)
        if (st) loadAa((t + 1) * BK);
        __builtin_amdgcn_sched_barrier(0);

        // MFMA half B (m 64..127) — consumes aFb(t)
        __builtin_amdgcn_s_setprio(1);
#pragma unroll
        for (int i = 0; i < 4; ++i)
#pragma unroll
            for (int j = 0; j < 4; ++j)
#pragma unroll
                for (int kk = 0; kk < 2; ++kk)
                    acc[4 + i][j] = __builtin_amdgcn_mfma_f32_16x16x32_bf16(
                        aFb[i][kk], bF[j][kk], acc[4 + i][j], 0, 0, 0);
        __builtin_amdgcn_s_setprio(0);
        __builtin_amdgcn_sched_barrier(0);
        if (st) loadAb((t + 1) * BK);
        __builtin_amdgcn_sched_barrier(0);
    }

    // epilogue: C/D layout col = lane&15, row = (lane>>4)*4 + r
#pragma unroll
    for (int j = 0; j < 4; ++j) {
        int col = n0 + wv * 64 + j * 16 + lr;
        float bv = bias[col];
#pragma unroll
        for (int i = 0; i < 8; ++i) {
            int row = m0 + i * 16 + lk * 4;
#pragma unroll
            for (int r = 0; r < 4; ++r)
                C[(size_t)(row + r) * N + col] = acc[i][j][r] + bv;
        }
    }
}

extern "C" void kernel_launch(void* const* d_in, const int* in_sizes, int n_in,
                              void* d_out, int out_size, void* d_ws, size_t ws_size,
                              hipStream_t stream) {
    const float* x      = (const float*)d_in[0];
    const int*   binary = (const int*)d_in[1];
    const float* scale  = (const float*)d_in[2];
    const float* bias   = (const float*)d_in[3];
    float* out = (float*)d_out;

    const int M = in_sizes[0] / NXX;   // 4096 tokens

    __hip_bfloat16* xb = (__hip_bfloat16*)d_ws;                 // 8 MB
    __hip_bfloat16* Wb = xb + (size_t)M * NXX;                  // 8 MB

    k_prep<<<2048 + (NF * GRP) / 256, 256, 0, stream>>>(x, binary, scale, xb, Wb);
    k_gemm<<<(M / BM) * (NF / BN), 256, 0, stream>>>(xb, Wb, bias, out, M, NF, NXX);
}

// Round 6
// 131.118 us; speedup vs baseline: 1.5347x; 1.5347x over previous
//
#include <hip/hip_runtime.h>
#include <hip/hip_bf16.h>
#include <stdint.h>

// out = x @ W^T + bias; W[f,n] = sum_k scale[k,f]*(bit(7-n%8) of binary[k,f,n/8] ? +1 : -1)
// Round 6: 256x256 8-wave GEMM, 8 phases/K-tile over 32-row A-QUARTERS with a
// 2-deep A-frag register ring (aS0/aS1) + B frags loaded once/tile (bF0/bF1).
// Fixes the WAR hazard that re-serialized rounds 2-4: every frag reload now has
// >=2 phases of distance from its readers, and adjacent phases write disjoint
// acc quadrants, so MFMA pipe never drains at phase edges. Stage ring with
// derived counted vmcnt (6@p0, 8@p7; tail-peeled 4/0). T1+T2 kept.

#define BITS 8
#define NF   4096
#define NXX  1024
#define GRP  (NXX / 8)

#define BM 256
#define BN 256
#define BK 64
#define NTHR 512

typedef __attribute__((ext_vector_type(4))) float f32x4;
typedef __attribute__((ext_vector_type(8))) short bf16x8;

// ---------------- prep: cast x (blocks 0..2047) + decode W (blocks 2048..4095) ----
__global__ __launch_bounds__(256) void k_prep(const float* __restrict__ x,
                                              const int* __restrict__ binary,
                                              const float* __restrict__ scale,
                                              __hip_bfloat16* __restrict__ xb,
                                              __hip_bfloat16* __restrict__ Wb) {
    const int b = blockIdx.x;
    const int tid = threadIdx.x;
    if (b < 2048) {
        int i = b * 256 + tid;
        const float4* xp = (const float4*)x;
        float4 a = xp[2 * i], c = xp[2 * i + 1];
        union { __hip_bfloat16 h[8]; int4 v; } u;
        u.h[0] = __float2bfloat16(a.x);
        u.h[1] = __float2bfloat16(a.y);
        u.h[2] = __float2bfloat16(a.z);
        u.h[3] = __float2bfloat16(a.w);
        u.h[4] = __float2bfloat16(c.x);
        u.h[5] = __float2bfloat16(c.y);
        u.h[6] = __float2bfloat16(c.z);
        u.h[7] = __float2bfloat16(c.w);
        ((int4*)xb)[i] = u.v;
    } else {
        int idx = (b - 2048) * 256 + tid;       // 0 .. NF*GRP-1
        int f = idx >> 7;                       // GRP = 128
        int g = idx & (GRP - 1);
        float sc[BITS];
        int   bv[BITS];
#pragma unroll
        for (int k = 0; k < BITS; ++k) {
            sc[k] = scale[k * NF + f];
            bv[k] = binary[(size_t)(k * NF + f) * GRP + g];
        }
        union { __hip_bfloat16 h[8]; int4 v; } u;
#pragma unroll
        for (int j = 0; j < 8; ++j) {           // element j uses bit (7-j)
            float s = 0.f;
#pragma unroll
            for (int k = 0; k < BITS; ++k)
                s += ((bv[k] >> (7 - j)) & 1) ? sc[k] : -sc[k];
            u.h[j] = __float2bfloat16(s);
        }
        ((int4*)Wb)[idx] = u.v;
    }
}

// ---------------- GEMM: C[M,N] = A[M,K] * B[N,K]^T + bias ----------------
// 512 thr = 8 waves (2M x 4N), wave-tile 128x64, acc[8][4] f32x4.
// LDS: 2 bufs x (A 32KB + B 32KB) = 128 KB.
// Units: A_f rows {0-63,128-191} (A-quarters 0,1 of both wm), A_b the rest,
//        B_f = ns0 rows (wn*64+0..31), B_b = ns1 rows.
// Phases: p0 q(0,0) [ld aS0,bF0; stage A_b(t+1); vmcnt6]  p1 q(0,1) [ld bF1; stage B_b(t+1)]
//         p2 q(1,0) [ld aS1]  p3 q(1,1)  p4+p5 q(2,0),q(2,1) [ld aS0; stage A_f(t+2)]
//         p6 q(3,0) [ld aS1]  p7 q(3,1) [stage B_f(t+2); vmcnt8]
__global__ __launch_bounds__(NTHR, 2) void k_gemm(const __hip_bfloat16* __restrict__ A,
                                                  const __hip_bfloat16* __restrict__ B,
                                                  const float* __restrict__ bias,
                                                  float* __restrict__ C,
                                                  int M, int N, int K) {
    __shared__ __align__(16) char lds[131072];

    const int tid  = threadIdx.x;
    const int lane = tid & 63;
    const int wid  = tid >> 6;
    const int wm = wid >> 2;        // 0..1
    const int wn = wid & 3;         // 0..3
    const int lr = lane & 15;       // fragment row/col
    const int lk = lane >> 4;       // K-octet 0..3

    // T1: XCD-aware swizzle (grid=256 -> 32/XCD, bijective)
    const int nwg = gridDim.x;
    const int cpx = nwg >> 3;
    const int bid = blockIdx.x;
    const int swz = (bid & 7) * cpx + (bid >> 3);
    const int m0 = (swz >> 4) * BM;
    const int n0 = (swz & 15) * BN;

    const int NT = K / BK;          // 16 K-tiles

    // ---- half-tile stage: kind 0=A_f 1=A_b 2=B_f 3=B_b; 2 gload_lds/thread ----
    auto stage_unit = [&](int buf, int kt, int kind) {
        const bool isA = (kind < 2);
        const __hip_bfloat16* src = (isA ? A + (size_t)m0 * K : B + (size_t)n0 * K) + kt;
        char* base = lds + buf * 65536 + (isA ? 0 : 32768);
        int lrr = tid >> 3;          // 0..63
        int q   = tid & 7;
        int R0;
        if (isA) R0 = ((kind == 1) ? 64 : 0) + lrr;
        else     R0 = ((kind == 3) ? 32 : 0) + (lrr & 31) + ((lrr & 32) << 1);
#pragma unroll
        for (int call = 0; call < 2; ++call) {
            int R  = R0 + call * 128;
            int qs = q ^ (R & 7);            // pre-swizzled source (T2, rule #21)
            __builtin_amdgcn_global_load_lds(
                (const __attribute__((address_space(1))) void*)(src + (size_t)R * K + qs * 8),
                (__attribute__((address_space(3))) void*)(base + R * 128 + q * 16), 16, 0, 0);
        }
    };
    // swizzled LDS reads: logical (row R, col-byte CB) -> CB ^ ((R&7)<<4)
    auto ldA = [&](int buf, int qr, int i, int kk) -> bf16x8 {   // qr = 32-row quarter
        int R = wm * 128 + qr * 32 + i * 16 + lr;
        int CB = (kk * 64 + lk * 16) ^ ((R & 7) << 4);
        return *(const bf16x8*)(lds + buf * 65536 + R * 128 + CB);
    };
    auto ldB = [&](int buf, int ns, int j, int kk) -> bf16x8 {
        int R = wn * 64 + ns * 32 + j * 16 + lr;
        int CB = (kk * 64 + lk * 16) ^ ((R & 7) << 4);
        return *(const bf16x8*)(lds + buf * 65536 + 32768 + R * 128 + CB);
    };

    f32x4 acc[8][4] = {};
    bf16x8 aS0[2][2], aS1[2][2], bF0[2][2], bF1[2][2];

#define BAR()   __builtin_amdgcn_s_barrier()
#define SB0()   __builtin_amdgcn_sched_barrier(0)
#define LGKM0() do { asm volatile("s_waitcnt lgkmcnt(0)" ::: "memory"); SB0(); } while (0)
#define PRIO1() __builtin_amdgcn_s_setprio(1)
#define PRIO0() do { __builtin_amdgcn_s_setprio(0); SB0(); } while (0)
#define LDA2(D, b, qr) do { \
    D[0][0] = ldA(b, qr, 0, 0); D[0][1] = ldA(b, qr, 0, 1); \
    D[1][0] = ldA(b, qr, 1, 0); D[1][1] = ldA(b, qr, 1, 1); } while (0)
#define LDB2(D, b, ns) do { \
    D[0][0] = ldB(b, ns, 0, 0); D[0][1] = ldB(b, ns, 0, 1); \
    D[1][0] = ldB(b, ns, 1, 0); D[1][1] = ldB(b, ns, 1, 1); } while (0)
#define QUAD(mq, nq, AS, BF)                                                       \
    do {                                                                           \
        _Pragma("unroll") for (int i = 0; i < 2; ++i)                              \
        _Pragma("unroll") for (int j = 0; j < 2; ++j)                              \
        _Pragma("unroll") for (int kk = 0; kk < 2; ++kk)                           \
            acc[(mq)*2 + i][(nq)*2 + j] = __builtin_amdgcn_mfma_f32_16x16x32_bf16( \
                AS[i][kk], BF[j][kk], acc[(mq)*2 + i][(nq)*2 + j], 0, 0, 0);       \
    } while (0)

    // ---- prologue: issue order must match steady-state ring ----
    stage_unit(0, 0, 0);            // A_f(0)
    stage_unit(0, 0, 2);            // B_f(0)
    stage_unit(0, 0, 1);            // A_b(0)
    stage_unit(0, 0, 3);            // B_b(0)
    stage_unit(1, BK, 0);           // A_f(1)
    stage_unit(1, BK, 2);           // B_f(1)
    asm volatile("s_waitcnt vmcnt(8)" ::: "memory");   // retire A_f(0), B_f(0)
    BAR(); SB0();

    for (int t = 0; t < NT; ++t) {
        const int b = t & 1;
        const int o = b ^ 1;

        // ---- p0: q(0,0); ld aS0<-A.q0, bF0<-B.ns0; stage A_b(t+1) ----
        LDA2(aS0, b, 0);
        LDB2(bF0, b, 0);
        if (t <= NT - 2) stage_unit(o, (t + 1) * BK, 1);
        BAR(); LGKM0();
        PRIO1(); QUAD(0, 0, aS0, bF0); PRIO0();
        if (t < NT - 1) { asm volatile("s_waitcnt vmcnt(6)" ::: "memory"); }
        else            { asm volatile("s_waitcnt vmcnt(0)" ::: "memory"); }
        BAR(); SB0();

        // ---- p1: q(0,1); ld bF1<-B.ns1; stage B_b(t+1) ----
        LDB2(bF1, b, 1);
        if (t <= NT - 2) stage_unit(o, (t + 1) * BK, 3);
        BAR(); LGKM0();
        PRIO1(); QUAD(0, 1, aS0, bF1); PRIO0();

        // ---- p2: q(1,0); ld aS1<-A.q1 ----
        LDA2(aS1, b, 1);
        BAR(); LGKM0();
        PRIO1(); QUAD(1, 0, aS1, bF0); PRIO0();

        // ---- p3: q(1,1) (barrier required: separates p2 reads from p4 stage) ----
        BAR();
        PRIO1(); QUAD(1, 1, aS1, bF1); PRIO0();

        // ---- p4+p5: q(2,0), q(2,1); ld aS0<-A.q2; stage A_f(t+2) ----
        LDA2(aS0, b, 2);
        if (t <= NT - 3) stage_unit(b, (t + 2) * BK, 0);
        BAR(); LGKM0();
        PRIO1(); QUAD(2, 0, aS0, bF0); QUAD(2, 1, aS0, bF1); PRIO0();

        // ---- p6: q(3,0); ld aS1<-A.q3 ----
        LDA2(aS1, b, 3);
        BAR(); LGKM0();
        PRIO1(); QUAD(3, 0, aS1, bF0); PRIO0();

        // ---- p7: q(3,1); stage B_f(t+2); retire A_f/B_f(t+1) ----
        if (t <= NT - 3) stage_unit(b, (t + 2) * BK, 2);
        BAR();
        PRIO1(); QUAD(3, 1, aS1, bF1); PRIO0();
        if (t <= NT - 3)      { asm volatile("s_waitcnt vmcnt(8)" ::: "memory"); }
        else if (t == NT - 2) { asm volatile("s_waitcnt vmcnt(4)" ::: "memory"); }
        BAR(); SB0();
    }

#undef BAR
#undef SB0
#undef LGKM0
#undef PRIO1
#undef PRIO0
#undef LDA2
#undef LDB2
#undef QUAD

    // epilogue: C/D layout col = lane&15, row = (lane>>4)*4 + r
#pragma unroll
    for (int j = 0; j < 4; ++j) {
        int col = n0 + wn * 64 + j * 16 + lr;
        float bv = bias[col];
#pragma unroll
        for (int i = 0; i < 8; ++i) {
            int row = m0 + wm * 128 + i * 16 + lk * 4;
#pragma unroll
            for (int r = 0; r < 4; ++r)
                C[(size_t)(row + r) * N + col] = acc[i][j][r] + bv;
        }
    }
}

extern "C" void kernel_launch(void* const* d_in, const int* in_sizes, int n_in,
                              void* d_out, int out_size, void* d_ws, size_t ws_size,
                              hipStream_t stream) {
    const float* x      = (const float*)d_in[0];
    const int*   binary = (const int*)d_in[1];
    const float* scale  = (const float*)d_in[2];
    const float* bias   = (const float*)d_in[3];
    float* out = (float*)d_out;

    const int M = in_sizes[0] / NXX;   // 4096 tokens

    __hip_bfloat16* xb = (__hip_bfloat16*)d_ws;                 // 8 MB
    __hip_bfloat16* Wb = xb + (size_t)M * NXX;                  // 8 MB

    k_prep<<<2048 + (NF * GRP) / 256, 256, 0, stream>>>(x, binary, scale, xb, Wb);
    k_gemm<<<(M / BM) * (NF / BN), NTHR, 0, stream>>>(xb, Wb, bias, out, M, NF, NXX);
}